// Round 1
// baseline (501.195 us; speedup 1.0000x reference)
//
#include <hip/hip_runtime.h>

#define N_NODES 100000
#define C_IN 128
#define C_OUT 32

// ---------------- degree count ----------------
__global__ void count_deg_kernel(const int* __restrict__ dst, int E, int* __restrict__ cnt) {
    int i = blockIdx.x * blockDim.x + threadIdx.x;
    if (i < E) atomicAdd(&cnt[dst[i]], 1);
}

__global__ void dinv_kernel(const int* __restrict__ cnt, float* __restrict__ dinv, int n) {
    int i = blockIdx.x * blockDim.x + threadIdx.x;
    if (i < n) dinv[i] = rsqrtf((float)(cnt[i] + 1));  // +1 = self loop
}

// ---------------- GEMM1: h = x @ W1  (N x 128) @ (128 x 32) ----------------
__global__ __launch_bounds__(256) void gemm1_kernel(const float* __restrict__ x,
                                                    const float* __restrict__ W,
                                                    float* __restrict__ h, int n) {
    __shared__ float Ws[C_IN * C_OUT];  // 16 KB
    for (int i = threadIdx.x; i < (C_IN * C_OUT) / 4; i += 256)
        ((float4*)Ws)[i] = ((const float4*)W)[i];
    __syncthreads();

    int t = blockIdx.x * 256 + threadIdx.x;
    int row = t >> 5;
    if (row >= n) return;
    int c = t & 31;
    const float4* xr = (const float4*)(x + (size_t)row * C_IN);
    float acc = 0.f;
#pragma unroll
    for (int k4 = 0; k4 < C_IN / 4; ++k4) {
        float4 xv = xr[k4];
        acc = fmaf(xv.x, Ws[(k4 * 4 + 0) * C_OUT + c], acc);
        acc = fmaf(xv.y, Ws[(k4 * 4 + 1) * C_OUT + c], acc);
        acc = fmaf(xv.z, Ws[(k4 * 4 + 2) * C_OUT + c], acc);
        acc = fmaf(xv.w, Ws[(k4 * 4 + 3) * C_OUT + c], acc);
    }
    h[(size_t)row * C_OUT + c] = acc;
}

// ---------------- GEMM2: h2 = relu(a) @ W2  (N x 32) @ (32 x 32) ----------------
__global__ __launch_bounds__(256) void gemm2_relu_kernel(const float* __restrict__ a,
                                                         const float* __restrict__ W,
                                                         float* __restrict__ h, int n) {
    __shared__ float Ws[C_OUT * C_OUT];  // 4 KB
    for (int i = threadIdx.x; i < (C_OUT * C_OUT) / 4; i += 256)
        ((float4*)Ws)[i] = ((const float4*)W)[i];
    __syncthreads();

    int t = blockIdx.x * 256 + threadIdx.x;
    int row = t >> 5;
    if (row >= n) return;
    int c = t & 31;
    const float4* ar = (const float4*)(a + (size_t)row * C_OUT);
    float acc = 0.f;
#pragma unroll
    for (int k4 = 0; k4 < C_OUT / 4; ++k4) {
        float4 av = ar[k4];
        float a0 = fmaxf(av.x, 0.f);
        float a1 = fmaxf(av.y, 0.f);
        float a2 = fmaxf(av.z, 0.f);
        float a3 = fmaxf(av.w, 0.f);
        acc = fmaf(a0, Ws[(k4 * 4 + 0) * C_OUT + c], acc);
        acc = fmaf(a1, Ws[(k4 * 4 + 1) * C_OUT + c], acc);
        acc = fmaf(a2, Ws[(k4 * 4 + 2) * C_OUT + c], acc);
        acc = fmaf(a3, Ws[(k4 * 4 + 3) * C_OUT + c], acc);
    }
    h[(size_t)row * C_OUT + c] = acc;
}

// ---------------- self-loop + bias init: out[i,c] = h[i,c]*dinv[i]^2 + b[c] ----------------
__global__ void selfloop_bias_kernel(const float* __restrict__ h, const float* __restrict__ dinv,
                                     const float* __restrict__ b, float* __restrict__ out, int n) {
    int t = blockIdx.x * blockDim.x + threadIdx.x;
    if (t >= n * C_OUT) return;
    int i = t >> 5;
    int c = t & 31;
    float di = dinv[i];
    out[t] = h[t] * di * di + b[c];
}

// ---------------- scatter: out[d,:] += h[s,:] * dinv[s]*dinv[d] ----------------
__global__ void scatter_kernel(const int* __restrict__ src, const int* __restrict__ dst, int E,
                               const float* __restrict__ dinv, const float* __restrict__ h,
                               float* __restrict__ out) {
    int t = blockIdx.x * blockDim.x + threadIdx.x;
    int e = t >> 5;
    if (e >= E) return;
    int c = t & 31;
    int s = src[e];
    int d = dst[e];
    float norm = dinv[s] * dinv[d];
    float v = h[(size_t)s * C_OUT + c] * norm;
    atomicAdd(&out[(size_t)d * C_OUT + c], v);
}

extern "C" void kernel_launch(void* const* d_in, const int* in_sizes, int n_in,
                              void* d_out, int out_size, void* d_ws, size_t ws_size,
                              hipStream_t stream) {
    const float* x  = (const float*)d_in[0];
    const int*   ei = (const int*)d_in[1];
    const float* W1 = (const float*)d_in[2];
    const float* b1 = (const float*)d_in[3];
    const float* W2 = (const float*)d_in[4];
    const float* b2 = (const float*)d_in[5];

    const int n = in_sizes[0] / C_IN;        // 100000
    const int E = in_sizes[1] / 2;           // 1600000
    const int* src = ei;
    const int* dst = ei + E;

    // workspace layout (bytes)
    char* ws = (char*)d_ws;
    int*   cnt  = (int*)ws;                       // n ints    = 400000 B
    float* dinv = (float*)(ws + 400000);          // n floats  = 400000 B
    float* h    = (float*)(ws + 800000);          // n*32 f32  = 12.8 MB (h1, then reused as h2)
    float* aout = (float*)d_out;                  // a1 accumulator lives in d_out, then final out

    // 1. degree
    hipMemsetAsync(cnt, 0, (size_t)n * sizeof(int), stream);
    count_deg_kernel<<<(E + 255) / 256, 256, 0, stream>>>(dst, E, cnt);
    // 2. h1 = x @ W1 (independent of degree)
    gemm1_kernel<<<(n * C_OUT) / 256, 256, 0, stream>>>(x, W1, h, n);
    // 3. dinv
    dinv_kernel<<<(n + 255) / 256, 256, 0, stream>>>(cnt, dinv, n);
    // 4. a1 = h1*dinv^2 + b1  (in d_out)
    selfloop_bias_kernel<<<(n * C_OUT + 255) / 256, 256, 0, stream>>>(h, dinv, b1, aout, n);
    // 5. scatter layer 1
    scatter_kernel<<<((size_t)E * 32 + 255) / 256, 256, 0, stream>>>(src, dst, E, dinv, h, aout);
    // 6. h2 = relu(a1) @ W2 (h buffer reused)
    gemm2_relu_kernel<<<(n * C_OUT) / 256, 256, 0, stream>>>(aout, W2, h, n);
    // 7. out = h2*dinv^2 + b2 (overwrites d_out)
    selfloop_bias_kernel<<<(n * C_OUT + 255) / 256, 256, 0, stream>>>(h, dinv, b2, aout, n);
    // 8. scatter layer 2
    scatter_kernel<<<((size_t)E * 32 + 255) / 256, 256, 0, stream>>>(src, dst, E, dinv, h, aout);
}

// Round 2
// 447.799 us; speedup vs baseline: 1.1192x; 1.1192x over previous
//
#include <hip/hip_runtime.h>

#define C_IN 128
#define C_OUT 32

// ================= degree / dinv =================
__global__ void count_deg_kernel(const int* __restrict__ dst, int E, int* __restrict__ cnt) {
    int i = blockIdx.x * blockDim.x + threadIdx.x;
    if (i < E) atomicAdd(&cnt[dst[i]], 1);
}

__global__ void dinv_kernel(const int* __restrict__ cnt, float* __restrict__ dinv, int n) {
    int i = blockIdx.x * blockDim.x + threadIdx.x;
    if (i < n) dinv[i] = rsqrtf((float)(cnt[i] + 1));  // +1 = self loop
}

// ================= exclusive scan (3-kernel) =================
__global__ __launch_bounds__(256) void scan_block_kernel(const int* __restrict__ cnt,
                                                         int* __restrict__ ptr,
                                                         int* __restrict__ bsums, int n) {
    __shared__ int tmp[256];
    int i = blockIdx.x * 256 + threadIdx.x;
    int v = (i < n) ? cnt[i] : 0;
    tmp[threadIdx.x] = v;
    __syncthreads();
    for (int off = 1; off < 256; off <<= 1) {
        int t = (threadIdx.x >= off) ? tmp[threadIdx.x - off] : 0;
        __syncthreads();
        tmp[threadIdx.x] += t;
        __syncthreads();
    }
    if (i < n) ptr[i] = tmp[threadIdx.x] - v;  // exclusive within block
    if (threadIdx.x == 255) bsums[blockIdx.x] = tmp[255];
}

__global__ __launch_bounds__(512) void scan_sums_kernel(int* __restrict__ bsums, int nb) {
    __shared__ int tmp[512];
    int v = (threadIdx.x < nb) ? bsums[threadIdx.x] : 0;
    tmp[threadIdx.x] = v;
    __syncthreads();
    for (int off = 1; off < 512; off <<= 1) {
        int t = (threadIdx.x >= off) ? tmp[threadIdx.x - off] : 0;
        __syncthreads();
        tmp[threadIdx.x] += t;
        __syncthreads();
    }
    if (threadIdx.x < nb) bsums[threadIdx.x] = tmp[threadIdx.x] - v;  // exclusive
}

__global__ __launch_bounds__(256) void scan_add_kernel(int* __restrict__ ptr, int* __restrict__ cursor,
                                                       const int* __restrict__ bsums, int n, int E) {
    int i = blockIdx.x * 256 + threadIdx.x;
    if (i < n) {
        int p = ptr[i] + bsums[blockIdx.x];
        ptr[i] = p;
        cursor[i] = p;
    }
    if (i == 0) ptr[n] = E;
}

// ================= CSR fill (group edges by dst, store src) =================
__global__ void fill_kernel(const int* __restrict__ src, const int* __restrict__ dst, int E,
                            int* __restrict__ cursor, int* __restrict__ srcs) {
    int e = blockIdx.x * blockDim.x + threadIdx.x;
    if (e >= E) return;
    int d = dst[e];
    int pos = atomicAdd(&cursor[d], 1);
    srcs[pos] = src[e];
}

// ================= GEMM1: h = x @ W1  (N x 128) @ (128 x 32) =================
__global__ __launch_bounds__(256) void gemm1_kernel(const float* __restrict__ x,
                                                    const float* __restrict__ W,
                                                    float* __restrict__ h, int n) {
    __shared__ float Ws[C_IN * C_OUT];  // 16 KB
    for (int i = threadIdx.x; i < (C_IN * C_OUT) / 4; i += 256)
        ((float4*)Ws)[i] = ((const float4*)W)[i];
    __syncthreads();

    int t = blockIdx.x * 256 + threadIdx.x;
    int row = t >> 5;
    if (row >= n) return;
    int c = t & 31;
    const float4* xr = (const float4*)(x + (size_t)row * C_IN);
    float acc = 0.f;
#pragma unroll
    for (int k4 = 0; k4 < C_IN / 4; ++k4) {
        float4 xv = xr[k4];
        acc = fmaf(xv.x, Ws[(k4 * 4 + 0) * C_OUT + c], acc);
        acc = fmaf(xv.y, Ws[(k4 * 4 + 1) * C_OUT + c], acc);
        acc = fmaf(xv.z, Ws[(k4 * 4 + 2) * C_OUT + c], acc);
        acc = fmaf(xv.w, Ws[(k4 * 4 + 3) * C_OUT + c], acc);
    }
    h[(size_t)row * C_OUT + c] = acc;
}

// ================= GEMM2: h2 = relu(a) @ W2  (N x 32) @ (32 x 32) =================
__global__ __launch_bounds__(256) void gemm2_relu_kernel(const float* __restrict__ a,
                                                         const float* __restrict__ W,
                                                         float* __restrict__ h, int n) {
    __shared__ float Ws[C_OUT * C_OUT];  // 4 KB
    for (int i = threadIdx.x; i < (C_OUT * C_OUT) / 4; i += 256)
        ((float4*)Ws)[i] = ((const float4*)W)[i];
    __syncthreads();

    int t = blockIdx.x * 256 + threadIdx.x;
    int row = t >> 5;
    if (row >= n) return;
    int c = t & 31;
    const float4* ar = (const float4*)(a + (size_t)row * C_OUT);
    float acc = 0.f;
#pragma unroll
    for (int k4 = 0; k4 < C_OUT / 4; ++k4) {
        float4 av = ar[k4];
        float a0 = fmaxf(av.x, 0.f);
        float a1 = fmaxf(av.y, 0.f);
        float a2 = fmaxf(av.z, 0.f);
        float a3 = fmaxf(av.w, 0.f);
        acc = fmaf(a0, Ws[(k4 * 4 + 0) * C_OUT + c], acc);
        acc = fmaf(a1, Ws[(k4 * 4 + 1) * C_OUT + c], acc);
        acc = fmaf(a2, Ws[(k4 * 4 + 2) * C_OUT + c], acc);
        acc = fmaf(a3, Ws[(k4 * 4 + 3) * C_OUT + c], acc);
    }
    h[(size_t)row * C_OUT + c] = acc;
}

// ================= gather-side aggregation =================
// one 64-lane wave per node; lanes = 2 edges x 32 channels
// out[v,c] = dinv[v] * sum_s dinv[s]*h[s,c]  +  dinv[v]^2 * h[v,c]  +  b[c]
__global__ __launch_bounds__(256) void aggregate_kernel(const float* __restrict__ h,
                                                        const float* __restrict__ dinv,
                                                        const int* __restrict__ ptr,
                                                        const int* __restrict__ srcs,
                                                        const float* __restrict__ b,
                                                        float* __restrict__ out, int n) {
    int wid = (blockIdx.x * 256 + threadIdx.x) >> 6;  // node = global wave id
    if (wid >= n) return;                             // wave-uniform
    int lane = threadIdx.x & 63;
    int half = lane >> 5;
    int c = lane & 31;
    int beg = ptr[wid], end = ptr[wid + 1];
    float acc = 0.f;
    for (int e = beg + half; e < end; e += 2) {
        int s = srcs[e];
        acc += dinv[s] * h[(size_t)s * C_OUT + c];
    }
    acc += __shfl_xor(acc, 32);  // combine the two edge-halves
    if (half == 0) {
        float dv = dinv[wid];
        out[(size_t)wid * C_OUT + c] = dv * acc + dv * dv * h[(size_t)wid * C_OUT + c] + b[c];
    }
}

// ================= fallback (R1 atomic path) =================
__global__ void selfloop_bias_kernel(const float* __restrict__ h, const float* __restrict__ dinv,
                                     const float* __restrict__ b, float* __restrict__ out, int n) {
    int t = blockIdx.x * blockDim.x + threadIdx.x;
    if (t >= n * C_OUT) return;
    int i = t >> 5;
    int c = t & 31;
    float di = dinv[i];
    out[t] = h[t] * di * di + b[c];
}

__global__ void scatter_kernel(const int* __restrict__ src, const int* __restrict__ dst, int E,
                               const float* __restrict__ dinv, const float* __restrict__ h,
                               float* __restrict__ out) {
    int t = blockIdx.x * blockDim.x + threadIdx.x;
    int e = t >> 5;
    if (e >= E) return;
    int c = t & 31;
    int s = src[e];
    int d = dst[e];
    float norm = dinv[s] * dinv[d];
    float v = h[(size_t)s * C_OUT + c] * norm;
    atomicAdd(&out[(size_t)d * C_OUT + c], v);
}

extern "C" void kernel_launch(void* const* d_in, const int* in_sizes, int n_in,
                              void* d_out, int out_size, void* d_ws, size_t ws_size,
                              hipStream_t stream) {
    const float* x  = (const float*)d_in[0];
    const int*   ei = (const int*)d_in[1];
    const float* W1 = (const float*)d_in[2];
    const float* b1 = (const float*)d_in[3];
    const float* W2 = (const float*)d_in[4];
    const float* b2 = (const float*)d_in[5];

    const int n = in_sizes[0] / C_IN;   // 100000
    const int E = in_sizes[1] / 2;      // 1600000
    const int* src = ei;
    const int* dst = ei + E;
    float* aout = (float*)d_out;

    const int nb_scan = (n + 255) / 256;  // 391

    // CSR workspace layout (1 MB-aligned regions)
    const size_t MB = 1024 * 1024;
    size_t need = 9 * MB + (size_t)n * C_OUT * sizeof(float);
    char* ws = (char*)d_ws;

    if (ws_size >= need) {
        int*   cnt    = (int*)(ws + 0);
        int*   ptr    = (int*)(ws + (size_t)(0.5 * MB));
        int*   cursor = (int*)(ws + 1 * MB);
        int*   bsums  = (int*)(ws + (size_t)(1.5 * MB));
        float* dinv   = (float*)(ws + 2 * MB);
        int*   srcs   = (int*)(ws + (size_t)(2.5 * MB));   // E ints = 6.4 MB
        float* h      = (float*)(ws + 9 * MB);             // n*32 f32 = 12.8 MB

        // ---- CSR build ----
        hipMemsetAsync(cnt, 0, (size_t)n * sizeof(int), stream);
        count_deg_kernel<<<(E + 255) / 256, 256, 0, stream>>>(dst, E, cnt);
        scan_block_kernel<<<nb_scan, 256, 0, stream>>>(cnt, ptr, bsums, n);
        scan_sums_kernel<<<1, 512, 0, stream>>>(bsums, nb_scan);
        scan_add_kernel<<<nb_scan, 256, 0, stream>>>(ptr, cursor, bsums, n, E);
        fill_kernel<<<(E + 255) / 256, 256, 0, stream>>>(src, dst, E, cursor, srcs);
        dinv_kernel<<<(n + 255) / 256, 256, 0, stream>>>(cnt, dinv, n);

        // ---- layer 1 ----
        gemm1_kernel<<<(n * C_OUT + 255) / 256, 256, 0, stream>>>(x, W1, h, n);
        aggregate_kernel<<<(n * 64 + 255) / 256, 256, 0, stream>>>(h, dinv, ptr, srcs, b1, aout, n);
        // ---- layer 2 ----
        gemm2_relu_kernel<<<(n * C_OUT + 255) / 256, 256, 0, stream>>>(aout, W2, h, n);
        aggregate_kernel<<<(n * 64 + 255) / 256, 256, 0, stream>>>(h, dinv, ptr, srcs, b2, aout, n);
    } else {
        // -------- fallback: R1 atomic path --------
        int*   cnt  = (int*)ws;
        float* dinv = (float*)(ws + 400000);
        float* h    = (float*)(ws + 800000);

        hipMemsetAsync(cnt, 0, (size_t)n * sizeof(int), stream);
        count_deg_kernel<<<(E + 255) / 256, 256, 0, stream>>>(dst, E, cnt);
        gemm1_kernel<<<(n * C_OUT + 255) / 256, 256, 0, stream>>>(x, W1, h, n);
        dinv_kernel<<<(n + 255) / 256, 256, 0, stream>>>(cnt, dinv, n);
        selfloop_bias_kernel<<<(n * C_OUT + 255) / 256, 256, 0, stream>>>(h, dinv, b1, aout, n);
        scatter_kernel<<<((size_t)E * 32 + 255) / 256, 256, 0, stream>>>(src, dst, E, dinv, h, aout);
        gemm2_relu_kernel<<<(n * C_OUT + 255) / 256, 256, 0, stream>>>(aout, W2, h, n);
        selfloop_bias_kernel<<<(n * C_OUT + 255) / 256, 256, 0, stream>>>(h, dinv, b2, aout, n);
        scatter_kernel<<<((size_t)E * 32 + 255) / 256, 256, 0, stream>>>(src, dst, E, dinv, h, aout);
    }
}